// Round 1
// baseline (527.337 us; speedup 1.0000x reference)
//
#include <hip/hip_runtime.h>
#include <hip/hip_bf16.h>

typedef __attribute__((ext_vector_type(4))) float  f32x4;
typedef __attribute__((ext_vector_type(4))) float  float4v;
typedef __attribute__((ext_vector_type(8))) short  s16x8;
typedef __attribute__((ext_vector_type(4))) short  s16x4;

constexpr int B_  = 4;
constexpr int S_  = 2048;
constexpr int D_  = 1024;
constexpr int H_  = 16;
constexpr int Dh_ = 64;
constexpr int M_  = B_ * S_;   // 8192 rows

static __device__ __forceinline__ unsigned short f2bf(float f) {
    union { float f; unsigned u; } v; v.f = f;
    unsigned r = v.u + 0x7fffu + ((v.u >> 16) & 1u);   // RNE
    return (unsigned short)(r >> 16);
}

// ---------------------------------------------------------------------------
// NT GEMM: C[m,n] = sum_k A[m,k] * W[n,k];  M=8192, N=1024, K=1024
// MODE 0: A = f32, C -> bf16 scattered to [B,H,S,Dh] (projection)
// MODE 1: A = bf16 ([B,S,D] row-major), C -> f32 linear [M,N] (output proj)
// 128x128 tile, BK=32, 4 waves, each wave does a 64x64 sub-tile (4x4 MFMA).
// ---------------------------------------------------------------------------
template <int MODE>
__global__ __launch_bounds__(256)
void gemm_nt(const void* __restrict__ Av, const float* __restrict__ W,
             void* __restrict__ Cv)
{
    constexpr int BK  = 32;
    constexpr int LDT = 40;                 // padded LDS row stride (elems), 80 B
    __shared__ unsigned short As[128 * LDT];
    __shared__ unsigned short Bs[128 * LDT];

    const int m0 = blockIdx.y * 128, n0 = blockIdx.x * 128;
    const int t = threadIdx.x;
    const int lane = t & 63, w = t >> 6;
    const int wr = (w >> 1) * 64, wc = (w & 1) * 64;
    const int lr = lane & 15, lg = lane >> 4;

    f32x4 acc[4][4] = {};

    for (int k0 = 0; k0 < 1024; k0 += BK) {
        // ---- stage A tile (128 x 32) as bf16 ----
        if (MODE == 0) {
            const float* A = (const float*)Av;
            #pragma unroll
            for (int j = 0; j < 4; ++j) {
                int e = j * 1024 + t * 4;
                int r = e >> 5, c = e & 31;
                float4v a = *(const float4v*)(A + (long)(m0 + r) * 1024 + k0 + c);
                union { unsigned short h[4]; unsigned long long u; } p;
                #pragma unroll
                for (int i = 0; i < 4; ++i) p.h[i] = f2bf(a[i]);
                *(unsigned long long*)(&As[r * LDT + c]) = p.u;
            }
        } else {
            const unsigned short* A = (const unsigned short*)Av;
            #pragma unroll
            for (int j = 0; j < 2; ++j) {
                int e = j * 2048 + t * 8;
                int r = e >> 5, c = e & 31;
                *(s16x8*)(&As[r * LDT + c]) =
                    *(const s16x8*)(A + (long)(m0 + r) * 1024 + k0 + c);
            }
        }
        // ---- stage W tile (128 x 32) as bf16 ----
        #pragma unroll
        for (int j = 0; j < 4; ++j) {
            int e = j * 1024 + t * 4;
            int r = e >> 5, c = e & 31;
            float4v b = *(const float4v*)(W + (long)(n0 + r) * 1024 + k0 + c);
            union { unsigned short h[4]; unsigned long long u; } p;
            #pragma unroll
            for (int i = 0; i < 4; ++i) p.h[i] = f2bf(b[i]);
            *(unsigned long long*)(&Bs[r * LDT + c]) = p.u;
        }
        __syncthreads();

        // ---- fragments + MFMA ----
        s16x8 af[4], bf[4];
        #pragma unroll
        for (int i = 0; i < 4; ++i)
            af[i] = *(const s16x8*)(&As[(wr + i * 16 + lr) * LDT + lg * 8]);
        #pragma unroll
        for (int i = 0; i < 4; ++i)
            bf[i] = *(const s16x8*)(&Bs[(wc + i * 16 + lr) * LDT + lg * 8]);
        #pragma unroll
        for (int mi = 0; mi < 4; ++mi)
            #pragma unroll
            for (int ni = 0; ni < 4; ++ni)
                acc[mi][ni] = __builtin_amdgcn_mfma_f32_16x16x32_bf16(
                    af[mi], bf[ni], acc[mi][ni], 0, 0, 0);
        __syncthreads();
    }

    // ---- epilogue ----
    if (MODE == 0) {
        unsigned short* Cb = (unsigned short*)Cv;   // [B,H,S,Dh]
        #pragma unroll
        for (int mi = 0; mi < 4; ++mi)
            #pragma unroll
            for (int ni = 0; ni < 4; ++ni) {
                int col = n0 + wc + ni * 16 + lr;
                int h = col >> 6, dh = col & 63;
                #pragma unroll
                for (int r = 0; r < 4; ++r) {
                    int row = m0 + wr + mi * 16 + lg * 4 + r;
                    int b = row >> 11, s = row & 2047;
                    Cb[(((long)b * H_ + h) * S_ + s) * Dh_ + dh] =
                        f2bf(acc[mi][ni][r]);
                }
            }
    } else {
        float* C = (float*)Cv;                      // [M, 1024] f32
        #pragma unroll
        for (int mi = 0; mi < 4; ++mi)
            #pragma unroll
            for (int ni = 0; ni < 4; ++ni) {
                int col = n0 + wc + ni * 16 + lr;
                #pragma unroll
                for (int r = 0; r < 4; ++r) {
                    int row = m0 + wr + mi * 16 + lg * 4 + r;
                    C[(long)row * 1024 + col] = acc[mi][ni][r];
                }
            }
    }
}

// ---------------------------------------------------------------------------
// Causal flash attention. 1 wave = one 16-row q-tile of one (b,h).
// Swapped QK^T: st = mfma(K_frag, Q_frag) -> st[k_row, q_col];
// score C-layout directly feeds PV's B operand (mfma_f32_16x16x16bf16_1k).
// O^T accumulated per dh-tile; epilogue writes [B,S,H,Dh] bf16.
// ---------------------------------------------------------------------------
__global__ __launch_bounds__(256)
void attn(const unsigned short* __restrict__ Qp, const unsigned short* __restrict__ Kp,
          const unsigned short* __restrict__ Vp, unsigned short* __restrict__ Op)
{
    const int t = threadIdx.x, lane = t & 63, w = t >> 6;
    const int tile = blockIdx.x * 4 + w;          // 0..8191
    const int qt = tile & 127, bh = tile >> 7;    // bh = b*H + h
    const int q0 = qt * 16;
    const int lr = lane & 15, lg = lane >> 4;

    const unsigned short* Qb = Qp + ((long)bh * S_ + q0) * Dh_;
    const unsigned short* Kb = Kp + (long)bh * S_ * Dh_;
    const unsigned short* Vb = Vp + (long)bh * S_ * Dh_;

    s16x8 qf0 = *(const s16x8*)(Qb + lr * Dh_ + lg * 8);
    s16x8 qf1 = *(const s16x8*)(Qb + lr * Dh_ + 32 + lg * 8);

    f32x4 acc[4] = {};                 // O^T dh-tiles: row dh = tt*16+lg*4+reg, col q = lr
    float mrun = -1e30f, lrun = 0.0f;

    const int ntiles = qt + 1;
    for (int kt = 0; kt < ntiles; ++kt) {
        const int k0 = kt * 16;
        s16x8 kf0 = *(const s16x8*)(Kb + (long)(k0 + lr) * Dh_ + lg * 8);
        s16x8 kf1 = *(const s16x8*)(Kb + (long)(k0 + lr) * Dh_ + 32 + lg * 8);
        f32x4 st = {};
        st = __builtin_amdgcn_mfma_f32_16x16x32_bf16(kf0, qf0, st, 0, 0, 0);
        st = __builtin_amdgcn_mfma_f32_16x16x32_bf16(kf1, qf1, st, 0, 0, 0);

        float s4[4];
        #pragma unroll
        for (int r = 0; r < 4; ++r) {
            float sc = st[r] * 0.125f;                     // 1/sqrt(64)
            if (kt == ntiles - 1 && (lg * 4 + r) > lr) sc = -1e30f;  // causal diag
            s4[r] = sc;
        }
        float tm = fmaxf(fmaxf(s4[0], s4[1]), fmaxf(s4[2], s4[3]));
        tm = fmaxf(tm, __shfl_xor(tm, 16));
        tm = fmaxf(tm, __shfl_xor(tm, 32));
        float mnew = fmaxf(mrun, tm);
        float f = __expf(mrun - mnew);

        float psum = 0.0f;
        unsigned short pb[4];
        #pragma unroll
        for (int r = 0; r < 4; ++r) {
            float p = __expf(s4[r] - mnew);
            psum += p;
            pb[r] = f2bf(p);
        }
        psum += __shfl_xor(psum, 16);
        psum += __shfl_xor(psum, 32);
        lrun = lrun * f + psum;
        mrun = mnew;
        #pragma unroll
        for (int tt = 0; tt < 4; ++tt) acc[tt] *= f;

        s16x4 pv = { (short)pb[0], (short)pb[1], (short)pb[2], (short)pb[3] };
        #pragma unroll
        for (int tt = 0; tt < 4; ++tt) {
            const unsigned short* vb = Vb + (long)(k0 + lg * 4) * Dh_ + tt * 16 + lr;
            s16x4 vf = { (short)vb[0], (short)vb[Dh_], (short)vb[2 * Dh_], (short)vb[3 * Dh_] };
            acc[tt] = __builtin_amdgcn_mfma_f32_16x16x16bf16_1k(vf, pv, acc[tt], 0, 0, 0);
        }
    }

    const float inv = 1.0f / lrun;
    const int b = bh >> 4, h = bh & 15;
    unsigned short* ob = Op + (((long)b * S_ + q0 + lr) * H_ + h) * Dh_;
    #pragma unroll
    for (int tt = 0; tt < 4; ++tt) {
        union { unsigned short h4[4]; unsigned long long u; } pk;
        #pragma unroll
        for (int r = 0; r < 4; ++r) pk.h4[r] = f2bf(acc[tt][r] * inv);
        *(unsigned long long*)(ob + tt * 16 + lg * 4) = pk.u;
    }
}

// ---------------------------------------------------------------------------
extern "C" void kernel_launch(void* const* d_in, const int* in_sizes, int n_in,
                              void* d_out, int out_size, void* d_ws, size_t ws_size,
                              hipStream_t stream)
{
    const float* q  = (const float*)d_in[0];
    const float* k  = (const float*)d_in[1];
    const float* v  = (const float*)d_in[2];
    // d_in[3] = causal mask (tril) — hardcoded in attn kernel
    const float* Wq = (const float*)d_in[4];
    const float* Wk = (const float*)d_in[5];
    const float* Wv = (const float*)d_in[6];
    const float* Wo = (const float*)d_in[7];

    unsigned short* ws = (unsigned short*)d_ws;
    const long NE = (long)B_ * S_ * D_;           // 8388608 elems
    unsigned short* Qp = ws;                      // [B,H,S,Dh] bf16
    unsigned short* Kp = ws + NE;
    unsigned short* Vp = ws + 2 * NE;
    unsigned short* Op = ws + 3 * NE;             // [B,S,H,Dh] bf16

    dim3 grid(8, 64), blk(256);
    hipLaunchKernelGGL((gemm_nt<0>), grid, blk, 0, stream, q, Wq, Qp);
    hipLaunchKernelGGL((gemm_nt<0>), grid, blk, 0, stream, k, Wk, Kp);
    hipLaunchKernelGGL((gemm_nt<0>), grid, blk, 0, stream, v, Wv, Vp);
    hipLaunchKernelGGL(attn, dim3(2048), blk, 0, stream, Qp, Kp, Vp, Op);
    hipLaunchKernelGGL((gemm_nt<1>), grid, blk, 0, stream, Op, Wo, (float*)d_out);
}

// Round 2
// 526.351 us; speedup vs baseline: 1.0019x; 1.0019x over previous
//
#include <hip/hip_runtime.h>
#include <hip/hip_bf16.h>

typedef __attribute__((ext_vector_type(4))) float  f32x4;
typedef __attribute__((ext_vector_type(4))) float  float4v;
typedef __attribute__((ext_vector_type(8))) short  s16x8;
typedef __attribute__((ext_vector_type(4))) short  s16x4;
typedef unsigned short u16;

constexpr int B_  = 4;
constexpr int S_  = 2048;
constexpr int D_  = 1024;
constexpr int H_  = 16;
constexpr int Dh_ = 64;

static __device__ __forceinline__ u16 f2bf(float f) {
    union { float f; unsigned u; } v; v.f = f;
    unsigned r = v.u + 0x7fffu + ((v.u >> 16) & 1u);   // RNE
    return (u16)(r >> 16);
}

// ---------------------------------------------------------------------------
// NT GEMM: C[m,n] = sum_k A[m,k] * W[n,k];  M=8192, N=1024, K=1024
// MODE 0: A=f32, C -> bf16 [B,H,S,Dh]     (Q/K projection)
// MODE 1: A=bf16 [B,S,D], C -> f32 [M,N]  (output projection)
// MODE 2: A=f32, C -> bf16 [B,H,Dh,S]    (V projection, transposed for PV)
// ---------------------------------------------------------------------------
template <int MODE>
__global__ __launch_bounds__(256)
void gemm_nt(const void* __restrict__ Av, const float* __restrict__ W,
             void* __restrict__ Cv)
{
    constexpr int LDT = 40;                 // padded LDS row stride (elems)
    __shared__ u16 As[128 * LDT];
    __shared__ u16 Bs[128 * LDT];

    const int m0 = blockIdx.y * 128, n0 = blockIdx.x * 128;
    const int t = threadIdx.x;
    const int lane = t & 63, w = t >> 6;
    const int wr = (w >> 1) * 64, wc = (w & 1) * 64;
    const int lr = lane & 15, lg = lane >> 4;

    f32x4 acc[4][4] = {};

    for (int k0 = 0; k0 < 1024; k0 += 32) {
        // ---- stage A tile (128 x 32) as bf16 ----
        if (MODE != 1) {
            const float* A = (const float*)Av;
            #pragma unroll
            for (int j = 0; j < 4; ++j) {
                int e = j * 1024 + t * 4;
                int r = e >> 5, c = e & 31;
                float4v a = *(const float4v*)(A + (long)(m0 + r) * 1024 + k0 + c);
                union { u16 h[4]; unsigned long long u; } p;
                #pragma unroll
                for (int i = 0; i < 4; ++i) p.h[i] = f2bf(a[i]);
                *(unsigned long long*)(&As[r * LDT + c]) = p.u;
            }
        } else {
            const u16* A = (const u16*)Av;
            #pragma unroll
            for (int j = 0; j < 2; ++j) {
                int e = j * 2048 + t * 8;
                int r = e >> 5, c = e & 31;
                *(s16x8*)(&As[r * LDT + c]) =
                    *(const s16x8*)(A + (long)(m0 + r) * 1024 + k0 + c);
            }
        }
        // ---- stage W tile (128 x 32) as bf16 ----
        #pragma unroll
        for (int j = 0; j < 4; ++j) {
            int e = j * 1024 + t * 4;
            int r = e >> 5, c = e & 31;
            float4v b = *(const float4v*)(W + (long)(n0 + r) * 1024 + k0 + c);
            union { u16 h[4]; unsigned long long u; } p;
            #pragma unroll
            for (int i = 0; i < 4; ++i) p.h[i] = f2bf(b[i]);
            *(unsigned long long*)(&Bs[r * LDT + c]) = p.u;
        }
        __syncthreads();

        s16x8 af[4], bf[4];
        #pragma unroll
        for (int i = 0; i < 4; ++i)
            af[i] = *(const s16x8*)(&As[(wr + i * 16 + lr) * LDT + lg * 8]);
        #pragma unroll
        for (int i = 0; i < 4; ++i)
            bf[i] = *(const s16x8*)(&Bs[(wc + i * 16 + lr) * LDT + lg * 8]);
        #pragma unroll
        for (int mi = 0; mi < 4; ++mi)
            #pragma unroll
            for (int ni = 0; ni < 4; ++ni)
                acc[mi][ni] = __builtin_amdgcn_mfma_f32_16x16x32_bf16(
                    af[mi], bf[ni], acc[mi][ni], 0, 0, 0);
        __syncthreads();
    }

    // ---- epilogue ----
    if (MODE == 0) {
        u16* Cb = (u16*)Cv;                         // [B,H,S,Dh]
        #pragma unroll
        for (int mi = 0; mi < 4; ++mi)
            #pragma unroll
            for (int ni = 0; ni < 4; ++ni) {
                int col = n0 + wc + ni * 16 + lr;
                int h = col >> 6, dh = col & 63;
                #pragma unroll
                for (int r = 0; r < 4; ++r) {
                    int row = m0 + wr + mi * 16 + lg * 4 + r;
                    int b = row >> 11, s = row & 2047;
                    Cb[(((long)b * H_ + h) * S_ + s) * Dh_ + dh] =
                        f2bf(acc[mi][ni][r]);
                }
            }
    } else if (MODE == 2) {
        u16* Cb = (u16*)Cv;                         // [B,H,Dh,S]
        #pragma unroll
        for (int mi = 0; mi < 4; ++mi)
            #pragma unroll
            for (int ni = 0; ni < 4; ++ni) {
                int col = n0 + wc + ni * 16 + lr;
                int h = col >> 6, dh = col & 63;
                int row = m0 + wr + mi * 16 + lg * 4;   // 4 consecutive tokens
                int b = row >> 11, s = row & 2047;
                union { u16 h4[4]; unsigned long long u; } pk;
                #pragma unroll
                for (int r = 0; r < 4; ++r) pk.h4[r] = f2bf(acc[mi][ni][r]);
                *(unsigned long long*)
                    (&Cb[(((long)b * H_ + h) * Dh_ + dh) * S_ + s]) = pk.u;
            }
    } else {
        float* C = (float*)Cv;                      // [M, 1024] f32
        #pragma unroll
        for (int mi = 0; mi < 4; ++mi)
            #pragma unroll
            for (int ni = 0; ni < 4; ++ni) {
                int col = n0 + wc + ni * 16 + lr;
                #pragma unroll
                for (int r = 0; r < 4; ++r) {
                    int row = m0 + wr + mi * 16 + lg * 4 + r;
                    C[(long)row * 1024 + col] = acc[mi][ni][r];
                }
            }
    }
}

// ---------------------------------------------------------------------------
// Causal flash attention v2.
// 1 wave = 32 q-rows (2 x 16-row tiles); block = 4 waves = 128 q-rows of one
// (b,h). KB=64 keys per iteration: QK^T (16 MFMA x32) -> one softmax pass per
// q-tile -> PV (32 MFMA x16, V^T b64 loads shared across both q-tiles).
// ---------------------------------------------------------------------------
__global__ __launch_bounds__(256)
void attn(const u16* __restrict__ Qp, const u16* __restrict__ Kp,
          const u16* __restrict__ Vt, u16* __restrict__ Op)
{
    const int t = threadIdx.x, lane = t & 63, w = t >> 6;
    const int bh = blockIdx.x >> 4;
    const int qb = 15 - (blockIdx.x & 15);        // heavy blocks first
    const int q0 = qb * 128 + w * 32;
    const int lr = lane & 15, lg = lane >> 4;

    const u16* Qb = Qp + ((long)bh * S_ + q0) * Dh_;
    const u16* Kb = Kp + (long)bh * S_ * Dh_;
    const u16* Vb = Vt + (long)bh * Dh_ * S_;

    s16x8 qf[2][2];
    #pragma unroll
    for (int i = 0; i < 2; ++i)
        #pragma unroll
        for (int h = 0; h < 2; ++h)
            qf[i][h] = *(const s16x8*)(Qb + (i * 16 + lr) * Dh_ + h * 32 + lg * 8);

    f32x4 acc[2][4] = {};          // acc[i][tt][r] = O^T[dh=tt*16+lg*4+r][q=q0+i*16+lr]
    float mrun[2] = { -1e30f, -1e30f }, lrun[2] = { 0.0f, 0.0f };

    const int nkb = (q0 + 95) >> 6;
    for (int kb = 0; kb < nkb; ++kb) {
        const int k0 = kb * 64;

        // ---- QK^T over 4 k-tiles ----
        f32x4 st[2][4] = {};
        #pragma unroll
        for (int kt = 0; kt < 4; ++kt) {
            const u16* kr = Kb + (long)(k0 + kt * 16 + lr) * Dh_ + lg * 8;
            s16x8 kf0 = *(const s16x8*)(kr);
            s16x8 kf1 = *(const s16x8*)(kr + 32);
            #pragma unroll
            for (int i = 0; i < 2; ++i) {
                st[i][kt] = __builtin_amdgcn_mfma_f32_16x16x32_bf16(kf0, qf[i][0], st[i][kt], 0, 0, 0);
                st[i][kt] = __builtin_amdgcn_mfma_f32_16x16x32_bf16(kf1, qf[i][1], st[i][kt], 0, 0, 0);
            }
        }

        const bool needMask = (k0 + 63) > q0;
        s16x4 pb[2][4];
        #pragma unroll
        for (int i = 0; i < 2; ++i) {
            const int qg = q0 + i * 16 + lr;
            float sv[16];
            #pragma unroll
            for (int kt = 0; kt < 4; ++kt)
                #pragma unroll
                for (int r = 0; r < 4; ++r) {
                    float sc = st[i][kt][r] * 0.125f;
                    if (needMask && (k0 + kt * 16 + lg * 4 + r) > qg) sc = -1e30f;
                    sv[kt * 4 + r] = sc;
                }
            float tm = sv[0];
            #pragma unroll
            for (int e = 1; e < 16; ++e) tm = fmaxf(tm, sv[e]);
            tm = fmaxf(tm, __shfl_xor(tm, 16));
            tm = fmaxf(tm, __shfl_xor(tm, 32));
            float mnew = fmaxf(mrun[i], tm);
            float f = __expf(mrun[i] - mnew);
            float psum = 0.0f;
            #pragma unroll
            for (int kt = 0; kt < 4; ++kt) {
                u16 ph[4];
                #pragma unroll
                for (int r = 0; r < 4; ++r) {
                    float p = __expf(sv[kt * 4 + r] - mnew);
                    psum += p;
                    ph[r] = f2bf(p);
                }
                pb[i][kt] = (s16x4){ (short)ph[0], (short)ph[1], (short)ph[2], (short)ph[3] };
            }
            psum += __shfl_xor(psum, 16);
            psum += __shfl_xor(psum, 32);
            lrun[i] = lrun[i] * f + psum;
            mrun[i] = mnew;
            #pragma unroll
            for (int tt = 0; tt < 4; ++tt) acc[i][tt] *= f;
        }

        // ---- PV: V^T b64 loads shared across both q-tiles ----
        #pragma unroll
        for (int kt = 0; kt < 4; ++kt)
            #pragma unroll
            for (int tt = 0; tt < 4; ++tt) {
                const u16* vr = Vb + (long)(tt * 16 + lr) * S_ + k0 + kt * 16 + lg * 4;
                s16x4 vf = *(const s16x4*)(vr);
                acc[0][tt] = __builtin_amdgcn_mfma_f32_16x16x16bf16_1k(vf, pb[0][kt], acc[0][tt], 0, 0, 0);
                acc[1][tt] = __builtin_amdgcn_mfma_f32_16x16x16bf16_1k(vf, pb[1][kt], acc[1][tt], 0, 0, 0);
            }
    }

    // ---- epilogue: O[b, q, h, dh] bf16 ----
    const int b = bh >> 4, h = bh & 15;
    #pragma unroll
    for (int i = 0; i < 2; ++i) {
        const float inv = 1.0f / lrun[i];
        u16* ob = Op + (((long)b * S_ + q0 + i * 16 + lr) * H_ + h) * Dh_;
        #pragma unroll
        for (int tt = 0; tt < 4; ++tt) {
            union { u16 h4[4]; unsigned long long u; } pk;
            #pragma unroll
            for (int r = 0; r < 4; ++r) pk.h4[r] = f2bf(acc[i][tt][r] * inv);
            *(unsigned long long*)(ob + tt * 16 + lg * 4) = pk.u;
        }
    }
}

// ---------------------------------------------------------------------------
extern "C" void kernel_launch(void* const* d_in, const int* in_sizes, int n_in,
                              void* d_out, int out_size, void* d_ws, size_t ws_size,
                              hipStream_t stream)
{
    const float* q  = (const float*)d_in[0];
    const float* k  = (const float*)d_in[1];
    const float* v  = (const float*)d_in[2];
    // d_in[3] = causal mask — hardcoded
    const float* Wq = (const float*)d_in[4];
    const float* Wk = (const float*)d_in[5];
    const float* Wv = (const float*)d_in[6];
    const float* Wo = (const float*)d_in[7];

    u16* ws = (u16*)d_ws;
    const long NE = (long)B_ * S_ * D_;           // 8388608 elems
    u16* Qp = ws;                                  // [B,H,S,Dh]
    u16* Kp = ws + NE;
    u16* Vt = ws + 2 * NE;                         // [B,H,Dh,S]
    u16* Op = ws + 3 * NE;                         // [B,S,H,Dh]

    dim3 grid(8, 64), blk(256);
    hipLaunchKernelGGL((gemm_nt<0>), grid, blk, 0, stream, q, Wq, Qp);
    hipLaunchKernelGGL((gemm_nt<0>), grid, blk, 0, stream, k, Wk, Kp);
    hipLaunchKernelGGL((gemm_nt<2>), grid, blk, 0, stream, v, Wv, Vt);
    hipLaunchKernelGGL(attn, dim3(64 * 16), blk, 0, stream, Qp, Kp, Vt, Op);
    hipLaunchKernelGGL((gemm_nt<1>), grid, blk, 0, stream, Op, Wo, (float*)d_out);
}

// Round 3
// 366.559 us; speedup vs baseline: 1.4386x; 1.4359x over previous
//
#include <hip/hip_runtime.h>
#include <hip/hip_bf16.h>

typedef __attribute__((ext_vector_type(4))) float  f32x4;
typedef __attribute__((ext_vector_type(4))) float  float4v;
typedef __attribute__((ext_vector_type(8))) short  s16x8;
typedef __attribute__((ext_vector_type(4))) short  s16x4;
typedef unsigned short u16;

constexpr int B_  = 4;
constexpr int S_  = 2048;
constexpr int D_  = 1024;
constexpr int H_  = 16;
constexpr int Dh_ = 64;

static __device__ __forceinline__ u16 f2bf(float f) {
    union { float f; unsigned u; } v; v.f = f;
    unsigned r = v.u + 0x7fffu + ((v.u >> 16) & 1u);   // RNE
    return (u16)(r >> 16);
}

// ---------------------------------------------------------------------------
// NT GEMM: C[m,n] = sum_k A[m,k] * W[n,k];  M=8192, N=1024, K=1024
// MODE 0: A=f32, C -> bf16 [B,H,S,Dh]     (Q/K projection)
// MODE 1: A=bf16 [B,S,D], C -> f32 [M,N]  (output projection)
// MODE 2: A=f32, C -> bf16 [B,H,Dh,S]    (V projection, transposed for PV)
// ---------------------------------------------------------------------------
template <int MODE>
__global__ __launch_bounds__(256)
void gemm_nt(const void* __restrict__ Av, const float* __restrict__ W,
             void* __restrict__ Cv)
{
    constexpr int LDT = 40;                 // padded LDS row stride (elems)
    __shared__ u16 As[128 * LDT];
    __shared__ u16 Bs[128 * LDT];

    const int m0 = blockIdx.y * 128, n0 = blockIdx.x * 128;
    const int t = threadIdx.x;
    const int lane = t & 63, w = t >> 6;
    const int wr = (w >> 1) * 64, wc = (w & 1) * 64;
    const int lr = lane & 15, lg = lane >> 4;

    f32x4 acc[4][4] = {};

    for (int k0 = 0; k0 < 1024; k0 += 32) {
        // ---- stage A tile (128 x 32) as bf16 ----
        if (MODE != 1) {
            const float* A = (const float*)Av;
            #pragma unroll
            for (int j = 0; j < 4; ++j) {
                int e = j * 1024 + t * 4;
                int r = e >> 5, c = e & 31;
                float4v a = *(const float4v*)(A + (long)(m0 + r) * 1024 + k0 + c);
                union { u16 h[4]; unsigned long long u; } p;
                #pragma unroll
                for (int i = 0; i < 4; ++i) p.h[i] = f2bf(a[i]);
                *(unsigned long long*)(&As[r * LDT + c]) = p.u;
            }
        } else {
            const u16* A = (const u16*)Av;
            #pragma unroll
            for (int j = 0; j < 2; ++j) {
                int e = j * 2048 + t * 8;
                int r = e >> 5, c = e & 31;
                *(s16x8*)(&As[r * LDT + c]) =
                    *(const s16x8*)(A + (long)(m0 + r) * 1024 + k0 + c);
            }
        }
        // ---- stage W tile (128 x 32) as bf16 ----
        #pragma unroll
        for (int j = 0; j < 4; ++j) {
            int e = j * 1024 + t * 4;
            int r = e >> 5, c = e & 31;
            float4v b = *(const float4v*)(W + (long)(n0 + r) * 1024 + k0 + c);
            union { u16 h[4]; unsigned long long u; } p;
            #pragma unroll
            for (int i = 0; i < 4; ++i) p.h[i] = f2bf(b[i]);
            *(unsigned long long*)(&Bs[r * LDT + c]) = p.u;
        }
        __syncthreads();

        s16x8 af[4], bf[4];
        #pragma unroll
        for (int i = 0; i < 4; ++i)
            af[i] = *(const s16x8*)(&As[(wr + i * 16 + lr) * LDT + lg * 8]);
        #pragma unroll
        for (int i = 0; i < 4; ++i)
            bf[i] = *(const s16x8*)(&Bs[(wc + i * 16 + lr) * LDT + lg * 8]);
        #pragma unroll
        for (int mi = 0; mi < 4; ++mi)
            #pragma unroll
            for (int ni = 0; ni < 4; ++ni)
                acc[mi][ni] = __builtin_amdgcn_mfma_f32_16x16x32_bf16(
                    af[mi], bf[ni], acc[mi][ni], 0, 0, 0);
        __syncthreads();
    }

    // ---- epilogue ----
    if (MODE == 0) {
        u16* Cb = (u16*)Cv;                         // [B,H,S,Dh]
        #pragma unroll
        for (int mi = 0; mi < 4; ++mi)
            #pragma unroll
            for (int ni = 0; ni < 4; ++ni) {
                int col = n0 + wc + ni * 16 + lr;
                int h = col >> 6, dh = col & 63;
                #pragma unroll
                for (int r = 0; r < 4; ++r) {
                    int row = m0 + wr + mi * 16 + lg * 4 + r;
                    int b = row >> 11, s = row & 2047;
                    Cb[(((long)b * H_ + h) * S_ + s) * Dh_ + dh] =
                        f2bf(acc[mi][ni][r]);
                }
            }
    } else if (MODE == 2) {
        u16* Cb = (u16*)Cv;                         // [B,H,Dh,S]
        #pragma unroll
        for (int mi = 0; mi < 4; ++mi)
            #pragma unroll
            for (int ni = 0; ni < 4; ++ni) {
                int col = n0 + wc + ni * 16 + lr;
                int h = col >> 6, dh = col & 63;
                int row = m0 + wr + mi * 16 + lg * 4;   // 4 consecutive tokens
                int b = row >> 11, s = row & 2047;
                union { u16 h4[4]; unsigned long long u; } pk;
                #pragma unroll
                for (int r = 0; r < 4; ++r) pk.h4[r] = f2bf(acc[mi][ni][r]);
                *(unsigned long long*)
                    (&Cb[(((long)b * H_ + h) * Dh_ + dh) * S_ + s]) = pk.u;
            }
    } else {
        float* C = (float*)Cv;                      // [M, 1024] f32
        #pragma unroll
        for (int mi = 0; mi < 4; ++mi)
            #pragma unroll
            for (int ni = 0; ni < 4; ++ni) {
                int col = n0 + wc + ni * 16 + lr;
                #pragma unroll
                for (int r = 0; r < 4; ++r) {
                    int row = m0 + wr + mi * 16 + lg * 4 + r;
                    C[(long)row * 1024 + col] = acc[mi][ni][r];
                }
            }
    }
}

// ---------------------------------------------------------------------------
// Causal flash attention v3.
// 1 block = 1 wave = 32 q-rows (2 x 16-row tiles) of one (b,h).
// Grid = 4096 one-wave blocks, heaviest q-strips first (LPT backfill over the
// causal wedge -- fixes R1's 15% occupancy / grid-granularity imbalance).
// KB=64 keys/iter; softmax in exp2 domain (scale folded with log2e).
// ---------------------------------------------------------------------------
__global__ __launch_bounds__(64)
void attn(const u16* __restrict__ Qp, const u16* __restrict__ Kp,
          const u16* __restrict__ Vt, u16* __restrict__ Op)
{
    const int lane = threadIdx.x;
    const int qt = 63 - (int)(blockIdx.x >> 6);   // heavy strips first
    const int bh = blockIdx.x & 63;
    const int q0 = qt * 32;
    const int lr = lane & 15, lg = lane >> 4;

    const u16* Qb = Qp + ((long)bh * S_ + q0) * Dh_;
    const u16* Kb = Kp + (long)bh * S_ * Dh_;
    const u16* Vb = Vt + (long)bh * Dh_ * S_;

    s16x8 qf[2][2];
    #pragma unroll
    for (int i = 0; i < 2; ++i)
        #pragma unroll
        for (int h = 0; h < 2; ++h)
            qf[i][h] = *(const s16x8*)(Qb + (i * 16 + lr) * Dh_ + h * 32 + lg * 8);

    f32x4 acc[2][4] = {};          // acc[i][tt][r] = O^T[dh=tt*16+lg*4+r][q=q0+i*16+lr]
    float mrun[2] = { -1e30f, -1e30f }, lrun[2] = { 0.0f, 0.0f };

    const float SCL = 0.125f * 1.44269504089f;    // 1/sqrt(Dh) * log2(e)

    const int nkb = (q0 + 95) >> 6;
    for (int kb = 0; kb < nkb; ++kb) {
        const int k0 = kb * 64;

        // ---- QK^T over 4 k-tiles ----
        f32x4 st[2][4] = {};
        #pragma unroll
        for (int kt = 0; kt < 4; ++kt) {
            const u16* kr = Kb + (long)(k0 + kt * 16 + lr) * Dh_ + lg * 8;
            s16x8 kf0 = *(const s16x8*)(kr);
            s16x8 kf1 = *(const s16x8*)(kr + 32);
            #pragma unroll
            for (int i = 0; i < 2; ++i) {
                st[i][kt] = __builtin_amdgcn_mfma_f32_16x16x32_bf16(kf0, qf[i][0], st[i][kt], 0, 0, 0);
                st[i][kt] = __builtin_amdgcn_mfma_f32_16x16x32_bf16(kf1, qf[i][1], st[i][kt], 0, 0, 0);
            }
        }

        const bool needMask = (k0 + 63) > q0;
        s16x4 pb[2][4];
        #pragma unroll
        for (int i = 0; i < 2; ++i) {
            const int qg = q0 + i * 16 + lr;
            float sv[16];
            #pragma unroll
            for (int kt = 0; kt < 4; ++kt)
                #pragma unroll
                for (int r = 0; r < 4; ++r) {
                    float sc = st[i][kt][r] * SCL;        // exp2 domain
                    if (needMask && (k0 + kt * 16 + lg * 4 + r) > qg) sc = -1e30f;
                    sv[kt * 4 + r] = sc;
                }
            float tm = sv[0];
            #pragma unroll
            for (int e = 1; e < 16; ++e) tm = fmaxf(tm, sv[e]);
            tm = fmaxf(tm, __shfl_xor(tm, 16));
            tm = fmaxf(tm, __shfl_xor(tm, 32));
            float mnew = fmaxf(mrun[i], tm);
            float f = __builtin_amdgcn_exp2f(mrun[i] - mnew);
            float psum = 0.0f;
            #pragma unroll
            for (int kt = 0; kt < 4; ++kt) {
                u16 ph[4];
                #pragma unroll
                for (int r = 0; r < 4; ++r) {
                    float p = __builtin_amdgcn_exp2f(sv[kt * 4 + r] - mnew);
                    psum += p;
                    ph[r] = f2bf(p);
                }
                pb[i][kt] = (s16x4){ (short)ph[0], (short)ph[1], (short)ph[2], (short)ph[3] };
            }
            psum += __shfl_xor(psum, 16);
            psum += __shfl_xor(psum, 32);
            lrun[i] = lrun[i] * f + psum;
            mrun[i] = mnew;
            #pragma unroll
            for (int tt = 0; tt < 4; ++tt) acc[i][tt] *= f;
        }

        // ---- PV: V^T b64 loads shared across both q-tiles ----
        #pragma unroll
        for (int kt = 0; kt < 4; ++kt)
            #pragma unroll
            for (int tt = 0; tt < 4; ++tt) {
                const u16* vr = Vb + (long)(tt * 16 + lr) * S_ + k0 + kt * 16 + lg * 4;
                s16x4 vf = *(const s16x4*)(vr);
                acc[0][tt] = __builtin_amdgcn_mfma_f32_16x16x16bf16_1k(vf, pb[0][kt], acc[0][tt], 0, 0, 0);
                acc[1][tt] = __builtin_amdgcn_mfma_f32_16x16x16bf16_1k(vf, pb[1][kt], acc[1][tt], 0, 0, 0);
            }
    }

    // ---- epilogue: O[b, q, h, dh] bf16 ----
    const int b = bh >> 4, h = bh & 15;
    #pragma unroll
    for (int i = 0; i < 2; ++i) {
        const float inv = 1.0f / lrun[i];
        u16* ob = Op + (((long)b * S_ + q0 + i * 16 + lr) * H_ + h) * Dh_;
        #pragma unroll
        for (int tt = 0; tt < 4; ++tt) {
            union { u16 h4[4]; unsigned long long u; } pk;
            #pragma unroll
            for (int r = 0; r < 4; ++r) pk.h4[r] = f2bf(acc[i][tt][r] * inv);
            *(unsigned long long*)(ob + tt * 16 + lg * 4) = pk.u;
        }
    }
}

// ---------------------------------------------------------------------------
extern "C" void kernel_launch(void* const* d_in, const int* in_sizes, int n_in,
                              void* d_out, int out_size, void* d_ws, size_t ws_size,
                              hipStream_t stream)
{
    const float* q  = (const float*)d_in[0];
    const float* k  = (const float*)d_in[1];
    const float* v  = (const float*)d_in[2];
    // d_in[3] = causal mask — hardcoded
    const float* Wq = (const float*)d_in[4];
    const float* Wk = (const float*)d_in[5];
    const float* Wv = (const float*)d_in[6];
    const float* Wo = (const float*)d_in[7];

    u16* ws = (u16*)d_ws;
    const long NE = (long)B_ * S_ * D_;           // 8388608 elems
    u16* Qp = ws;                                  // [B,H,S,Dh]
    u16* Kp = ws + NE;
    u16* Vt = ws + 2 * NE;                         // [B,H,Dh,S]
    u16* Op = ws + 3 * NE;                         // [B,S,H,Dh]

    dim3 grid(8, 64), blk(256);
    hipLaunchKernelGGL((gemm_nt<0>), grid, blk, 0, stream, q, Wq, Qp);
    hipLaunchKernelGGL((gemm_nt<0>), grid, blk, 0, stream, k, Wk, Kp);
    hipLaunchKernelGGL((gemm_nt<2>), grid, blk, 0, stream, v, Wv, Vt);
    hipLaunchKernelGGL(attn, dim3(4096), dim3(64), 0, stream, Qp, Kp, Vt, Op);
    hipLaunchKernelGGL((gemm_nt<1>), grid, blk, 0, stream, Op, Wo, (float*)d_out);
}

// Round 4
// 342.217 us; speedup vs baseline: 1.5409x; 1.0711x over previous
//
#include <hip/hip_runtime.h>
#include <hip/hip_bf16.h>

typedef __attribute__((ext_vector_type(4))) float  f32x4;
typedef __attribute__((ext_vector_type(8))) short  s16x8;
typedef __attribute__((ext_vector_type(4))) short  s16x4;
typedef unsigned short u16;

constexpr int B_  = 4;
constexpr int S_  = 2048;
constexpr int D_  = 1024;
constexpr int H_  = 16;
constexpr int Dh_ = 64;

// 1/sqrt(Dh) * log2(e) folded into Q at projection time
#define QSCALE 0.18033688f

static __device__ __forceinline__ short fb(float f) {
    __hip_bfloat16 h = __float2bfloat16(f);
    return __builtin_bit_cast(short, h);
}

static __device__ __forceinline__ void gload16(const u16* g, u16* l) {
    __builtin_amdgcn_global_load_lds(
        (const __attribute__((address_space(1))) unsigned int*)g,
        (__attribute__((address_space(3))) unsigned int*)l, 16, 0, 0);
}

// ---------------------------------------------------------------------------
// f32 -> bf16 convert (for weight matrices), 8 elems/thread
// ---------------------------------------------------------------------------
__global__ __launch_bounds__(256)
void cvtW(const float* __restrict__ s0, const float* __restrict__ s1,
          const float* __restrict__ s2,
          u16* __restrict__ d0, u16* __restrict__ d1, u16* __restrict__ d2)
{
    const float* s = blockIdx.y == 0 ? s0 : (blockIdx.y == 1 ? s1 : s2);
    u16*         d = blockIdx.y == 0 ? d0 : (blockIdx.y == 1 ? d1 : d2);
    long i = ((long)blockIdx.x * 256 + threadIdx.x) * 8;
    f32x4 a = *(const f32x4*)(s + i), b = *(const f32x4*)(s + i + 4);
    s16x8 o;
    #pragma unroll
    for (int j = 0; j < 4; ++j) { o[j] = fb(a[j]); o[4 + j] = fb(b[j]); }
    *(s16x8*)(d + i) = o;
}

// ---------------------------------------------------------------------------
// NT GEMM: C[m,n] = sum_k A[m,k]*W[n,k]; M=8192, N=K=1024. 128x128 tile, BK=32,
// 4 waves. B (bf16 weights) staged via global_load_lds (linear LDS, pre-swizzled
// source). A: MODE 0/2 = f32 input, VGPR cvt + swizzled ds_write_b128;
// MODE 1 = bf16 input via global_load_lds.
// LDS XOR swizzle: LDS[row][c] = G[row][c ^ ((row>>1)&3)] (16B chunks).
// MODE 0: C -> bf16 [B,H,S,Dh] * oscale    (Q/K projection)
// MODE 2: C -> bf16 [B,H,Dh,S]             (V projection, transposed)
// MODE 1: C -> f32 [M,N]                   (output projection)
// ---------------------------------------------------------------------------
template <int MODE>
__global__ __launch_bounds__(256)
void gemm_bf(const void* __restrict__ Av, const u16* __restrict__ Wb,
             void* __restrict__ Cv, float oscale)
{
    __shared__ u16 As[128 * 32];
    __shared__ u16 Bs[128 * 32];

    const int m0 = blockIdx.y * 128, n0 = blockIdx.x * 128;
    const int t = threadIdx.x, lane = t & 63, w = t >> 6;
    const int wr = (w >> 1) * 64, wc = (w & 1) * 64;
    const int lr = lane & 15, lg = lane >> 4;

    const int srow = t >> 2;                         // 0..63
    const int cc   = (t & 3) ^ ((t >> 3) & 3);       // swizzled 16B chunk
    const int fcol = (lg ^ ((lr >> 1) & 3)) * 8;     // swizzled read col

    const u16* Brow = Wb + (long)(n0 + srow) * 1024 + cc * 8;
    f32x4 acc[4][4] = {};

    for (int k0 = 0; k0 < 1024; k0 += 32) {
        // ---- B tile via global_load_lds (2 chunks of 64 rows) ----
        gload16(Brow + k0,             Bs + w * 512);
        gload16(Brow + 64 * 1024 + k0, Bs + 2048 + w * 512);
        // ---- A tile ----
        if (MODE == 1) {
            const u16* Arow = (const u16*)Av + (long)(m0 + srow) * 1024 + cc * 8;
            gload16(Arow + k0,             As + w * 512);
            gload16(Arow + 64 * 1024 + k0, As + 2048 + w * 512);
        } else {
            const float* Af = (const float*)Av + (long)(m0 + srow) * 1024 + (t & 3) * 8;
            #pragma unroll
            for (int c = 0; c < 2; ++c) {
                const float* p = Af + (long)c * 64 * 1024 + k0;
                f32x4 a = *(const f32x4*)(p), b = *(const f32x4*)(p + 4);
                s16x8 o;
                #pragma unroll
                for (int j = 0; j < 4; ++j) { o[j] = fb(a[j]); o[4 + j] = fb(b[j]); }
                *(s16x8*)(&As[(c * 64 + srow) * 32 + cc * 8]) = o;
            }
        }
        __syncthreads();

        s16x8 af[4], bfr[4];
        #pragma unroll
        for (int i = 0; i < 4; ++i)
            af[i] = *(const s16x8*)(&As[(wr + i * 16 + lr) * 32 + fcol]);
        #pragma unroll
        for (int i = 0; i < 4; ++i)
            bfr[i] = *(const s16x8*)(&Bs[(wc + i * 16 + lr) * 32 + fcol]);
        #pragma unroll
        for (int mi = 0; mi < 4; ++mi)
            #pragma unroll
            for (int ni = 0; ni < 4; ++ni)
                acc[mi][ni] = __builtin_amdgcn_mfma_f32_16x16x32_bf16(
                    af[mi], bfr[ni], acc[mi][ni], 0, 0, 0);
        __syncthreads();
    }

    if (MODE == 0) {
        u16* Cb = (u16*)Cv;                          // [B,H,S,Dh]
        #pragma unroll
        for (int mi = 0; mi < 4; ++mi)
            #pragma unroll
            for (int ni = 0; ni < 4; ++ni) {
                int col = n0 + wc + ni * 16 + lr;
                int h = col >> 6, dh = col & 63;
                #pragma unroll
                for (int r = 0; r < 4; ++r) {
                    int row = m0 + wr + mi * 16 + lg * 4 + r;
                    int b = row >> 11, s = row & 2047;
                    Cb[(((long)b * H_ + h) * S_ + s) * Dh_ + dh] =
                        (u16)fb(acc[mi][ni][r] * oscale);
                }
            }
    } else if (MODE == 2) {
        u16* Cb = (u16*)Cv;                          // [B,H,Dh,S]
        #pragma unroll
        for (int mi = 0; mi < 4; ++mi)
            #pragma unroll
            for (int ni = 0; ni < 4; ++ni) {
                int col = n0 + wc + ni * 16 + lr;
                int h = col >> 6, dh = col & 63;
                int row = m0 + wr + mi * 16 + lg * 4;
                int b = row >> 11, s = row & 2047;
                union { short h4[4]; unsigned long long u; } pk;
                #pragma unroll
                for (int r = 0; r < 4; ++r) pk.h4[r] = fb(acc[mi][ni][r]);
                *(unsigned long long*)
                    (&Cb[(((long)b * H_ + h) * Dh_ + dh) * S_ + s]) = pk.u;
            }
    } else {
        float* C = (float*)Cv;                       // [M,1024] f32
        #pragma unroll
        for (int mi = 0; mi < 4; ++mi)
            #pragma unroll
            for (int ni = 0; ni < 4; ++ni) {
                int col = n0 + wc + ni * 16 + lr;
                #pragma unroll
                for (int r = 0; r < 4; ++r) {
                    int row = m0 + wr + mi * 16 + lg * 4 + r;
                    C[(long)row * 1024 + col] = acc[mi][ni][r];
                }
            }
    }
}

// ---------------------------------------------------------------------------
// Causal flash attention v4.
// 1 block = 1 wave. Each wave processes a BALANCED PAIR of 32-row q-strips
// (qt = pair and 63-pair -> uniform 33 k-blocks/wave). Grid 2048 = 8 waves/CU.
// Per 64-key block: V loads issued first, QK^T (prescaled Q, exp2 domain),
// K-prefetch for next block (ping-pong reg buffers), deferred-max softmax
// (skip rescale when max growth <= 8 in log2 domain), PV.
// ---------------------------------------------------------------------------
__global__ __launch_bounds__(64)
void attn(const u16* __restrict__ Qp, const u16* __restrict__ Kp,
          const u16* __restrict__ Vt, u16* __restrict__ Op)
{
    const int lane = threadIdx.x;
    const int bh = blockIdx.x & 63;
    const int pair = blockIdx.x >> 6;             // 0..31
    const int lr = lane & 15, lg = lane >> 4;
    const int b = bh >> 4, h = bh & 15;

    const u16* Kb = Kp + (long)bh * S_ * Dh_;
    const u16* Vb = Vt + (long)bh * Dh_ * S_;

    #pragma unroll 1
    for (int sp = 0; sp < 2; ++sp) {
        const int qt = sp ? (63 - pair) : pair;
        const int q0 = qt * 32;
        const u16* Qb = Qp + ((long)bh * S_ + q0) * Dh_;

        s16x8 qf[2][2];
        #pragma unroll
        for (int i = 0; i < 2; ++i)
            #pragma unroll
            for (int hh = 0; hh < 2; ++hh)
                qf[i][hh] = *(const s16x8*)(Qb + (i * 16 + lr) * Dh_ + hh * 32 + lg * 8);

        f32x4 acc[2][4] = {};
        float mrun[2] = { -1e30f, -1e30f }, lrun[2] = { 0.0f, 0.0f };
        const int nkb = (q0 + 95) >> 6;

        s16x8 kbufA[8], kbufB[8];
        auto loadK = [&](s16x8 (&buf)[8], int kblk) {
            const u16* kr = Kb + ((long)kblk * 64 + lr) * Dh_ + lg * 8;
            #pragma unroll
            for (int kt = 0; kt < 4; ++kt) {
                buf[kt * 2]     = *(const s16x8*)(kr + kt * 16 * Dh_);
                buf[kt * 2 + 1] = *(const s16x8*)(kr + kt * 16 * Dh_ + 32);
            }
        };
        loadK(kbufA, 0);

        auto step = [&](int kb, s16x8 (&cur)[8], s16x8 (&nxt)[8]) {
            const int k0 = kb * 64;
            // V loads first (consumed last -> latency hidden under QK+softmax)
            s16x4 vf[16];
            #pragma unroll
            for (int kt = 0; kt < 4; ++kt)
                #pragma unroll
                for (int tt = 0; tt < 4; ++tt)
                    vf[kt * 4 + tt] = *(const s16x4*)
                        (Vb + (long)(tt * 16 + lr) * S_ + k0 + kt * 16 + lg * 4);
            // QK^T (Q prescaled by 1/sqrt(Dh)*log2e)
            f32x4 st[2][4] = {};
            #pragma unroll
            for (int kt = 0; kt < 4; ++kt)
                #pragma unroll
                for (int i = 0; i < 2; ++i) {
                    st[i][kt] = __builtin_amdgcn_mfma_f32_16x16x32_bf16(
                        cur[kt * 2], qf[i][0], st[i][kt], 0, 0, 0);
                    st[i][kt] = __builtin_amdgcn_mfma_f32_16x16x32_bf16(
                        cur[kt * 2 + 1], qf[i][1], st[i][kt], 0, 0, 0);
                }
            // prefetch next K block (hidden under softmax+PV)
            if (kb + 1 < nkb) loadK(nxt, kb + 1);

            const bool dmask = (k0 + 63) > q0;
            s16x4 pb[2][4];
            #pragma unroll
            for (int i = 0; i < 2; ++i) {
                const int qg = q0 + i * 16 + lr;
                float sv[16];
                #pragma unroll
                for (int kt = 0; kt < 4; ++kt)
                    #pragma unroll
                    for (int r = 0; r < 4; ++r) {
                        float sc = st[i][kt][r];
                        if (dmask && (k0 + kt * 16 + lg * 4 + r) > qg) sc = -1e30f;
                        sv[kt * 4 + r] = sc;
                    }
                float tm = sv[0];
                #pragma unroll
                for (int e = 1; e < 16; ++e) tm = fmaxf(tm, sv[e]);
                tm = fmaxf(tm, __shfl_xor(tm, 16));
                tm = fmaxf(tm, __shfl_xor(tm, 32));
                // deferred max (T13): skip rescale unless growth > 8 (log2)
                float mnew = mrun[i];
                if (!__all(tm <= mrun[i] + 8.0f)) {
                    mnew = fmaxf(mrun[i], tm);
                    float f = __builtin_amdgcn_exp2f(mrun[i] - mnew);
                    lrun[i] *= f;
                    #pragma unroll
                    for (int tt = 0; tt < 4; ++tt) acc[i][tt] *= f;
                    mrun[i] = mnew;
                }
                float psum = 0.0f;
                #pragma unroll
                for (int kt = 0; kt < 4; ++kt) {
                    short ph[4];
                    #pragma unroll
                    for (int r = 0; r < 4; ++r) {
                        float p = __builtin_amdgcn_exp2f(sv[kt * 4 + r] - mnew);
                        psum += p;
                        ph[r] = fb(p);
                    }
                    pb[i][kt] = (s16x4){ ph[0], ph[1], ph[2], ph[3] };
                }
                psum += __shfl_xor(psum, 16);
                psum += __shfl_xor(psum, 32);
                lrun[i] += psum;
            }
            #pragma unroll
            for (int kt = 0; kt < 4; ++kt)
                #pragma unroll
                for (int tt = 0; tt < 4; ++tt) {
                    acc[0][tt] = __builtin_amdgcn_mfma_f32_16x16x16bf16_1k(
                        vf[kt * 4 + tt], pb[0][kt], acc[0][tt], 0, 0, 0);
                    acc[1][tt] = __builtin_amdgcn_mfma_f32_16x16x16bf16_1k(
                        vf[kt * 4 + tt], pb[1][kt], acc[1][tt], 0, 0, 0);
                }
        };

        for (int kb = 0; kb < nkb; kb += 2) {
            step(kb, kbufA, kbufB);
            if (kb + 1 < nkb) step(kb + 1, kbufB, kbufA);
        }

        // epilogue: O[b,q,h,dh] bf16
        #pragma unroll
        for (int i = 0; i < 2; ++i) {
            const float inv = 1.0f / lrun[i];
            u16* ob = Op + (((long)b * S_ + q0 + i * 16 + lr) * H_ + h) * Dh_;
            #pragma unroll
            for (int tt = 0; tt < 4; ++tt) {
                union { short h4[4]; unsigned long long u; } pk;
                #pragma unroll
                for (int r = 0; r < 4; ++r) pk.h4[r] = fb(acc[i][tt][r] * inv);
                *(unsigned long long*)(ob + tt * 16 + lg * 4) = pk.u;
            }
        }
    }
}

// ---------------------------------------------------------------------------
extern "C" void kernel_launch(void* const* d_in, const int* in_sizes, int n_in,
                              void* d_out, int out_size, void* d_ws, size_t ws_size,
                              hipStream_t stream)
{
    const float* q  = (const float*)d_in[0];
    const float* k  = (const float*)d_in[1];
    const float* v  = (const float*)d_in[2];
    // d_in[3] = causal mask — hardcoded
    const float* Wq = (const float*)d_in[4];
    const float* Wk = (const float*)d_in[5];
    const float* Wv = (const float*)d_in[6];
    const float* Wo = (const float*)d_in[7];

    u16* ws = (u16*)d_ws;
    const long NE = (long)B_ * S_ * D_;           // 8388608 elems
    const long WE = (long)D_ * D_;                // 1048576 elems
    u16* Qp = ws;                                  // [B,H,S,Dh]
    u16* Kp = ws + NE;
    u16* Vt = ws + 2 * NE;                         // [B,H,Dh,S]
    u16* Op = ws + 3 * NE;                         // [B,S,H,Dh]
    // transient W-bf16 buffers aliased into dead regions (ws stays 4*NE):
    u16* WqB = Op;            // dead before attn writes Op
    u16* WkB = Op + WE;
    u16* WvB = Op + 2 * WE;
    u16* WoB = Qp;            // Qp dead after attn

    dim3 gw(512, 3), gw1(512, 1), gg(8, 64), blk(256);
    hipLaunchKernelGGL(cvtW, gw, blk, 0, stream, Wq, Wk, Wv, WqB, WkB, WvB);
    hipLaunchKernelGGL((gemm_bf<0>), gg, blk, 0, stream, q, WqB, Qp, QSCALE);
    hipLaunchKernelGGL((gemm_bf<0>), gg, blk, 0, stream, k, WkB, Kp, 1.0f);
    hipLaunchKernelGGL((gemm_bf<2>), gg, blk, 0, stream, v, WvB, Vt, 1.0f);
    hipLaunchKernelGGL(attn, dim3(2048), dim3(64), 0, stream, Qp, Kp, Vt, Op);
    hipLaunchKernelGGL(cvtW, gw1, blk, 0, stream, Wo, Wo, Wo, WoB, WoB, WoB);
    hipLaunchKernelGGL((gemm_bf<1>), gg, blk, 0, stream, Op, WoB, (float*)d_out, 1.0f);
}

// Round 5
// 252.895 us; speedup vs baseline: 2.0852x; 1.3532x over previous
//
#include <hip/hip_runtime.h>
#include <hip/hip_bf16.h>

typedef __attribute__((ext_vector_type(4))) float  f32x4;
typedef __attribute__((ext_vector_type(8))) short  s16x8;
typedef __attribute__((ext_vector_type(4))) short  s16x4;
typedef unsigned short u16;

constexpr int B_  = 4;
constexpr int S_  = 2048;
constexpr int D_  = 1024;
constexpr int H_  = 16;
constexpr int Dh_ = 64;

// 1/sqrt(Dh) * log2(e) folded into Q at projection time
#define QSCALE 0.18033688f

static __device__ __forceinline__ short fb(float f) {
    __hip_bfloat16 h = __float2bfloat16(f);
    return __builtin_bit_cast(short, h);
}

static __device__ __forceinline__ void gload16(const u16* g, u16* l) {
    __builtin_amdgcn_global_load_lds(
        (const __attribute__((address_space(1))) unsigned int*)g,
        (__attribute__((address_space(3))) unsigned int*)l, 16, 0, 0);
}

// ---------------------------------------------------------------------------
// f32 -> bf16 convert (weights), 8 elems/thread
// ---------------------------------------------------------------------------
__global__ __launch_bounds__(256)
void cvtW(const float* __restrict__ s0, const float* __restrict__ s1,
          const float* __restrict__ s2,
          u16* __restrict__ d0, u16* __restrict__ d1, u16* __restrict__ d2)
{
    const float* s = blockIdx.y == 0 ? s0 : (blockIdx.y == 1 ? s1 : s2);
    u16*         d = blockIdx.y == 0 ? d0 : (blockIdx.y == 1 ? d1 : d2);
    long i = ((long)blockIdx.x * 256 + threadIdx.x) * 8;
    f32x4 a = *(const f32x4*)(s + i), b = *(const f32x4*)(s + i + 4);
    s16x8 o;
    #pragma unroll
    for (int j = 0; j < 4; ++j) { o[j] = fb(a[j]); o[4 + j] = fb(b[j]); }
    *(s16x8*)(d + i) = o;
}

// ---------------------------------------------------------------------------
// NT GEMM: C[m,n] = sum_k A[m,k]*W[n,k]; M=8192, N=K=1024. 128x128 tile, BK=32.
// MODE 0: C -> bf16 [B,H,S,Dh] * oscale            (Q projection)
// MODE 3: C -> bf16 K-tiles [bh][kb][r][swz]        (K, pre-swizzled for LDS)
// MODE 2: C -> bf16 V^T-tiles [bh][kb][dh][swz]     (V, pre-swizzled for LDS)
// MODE 1: C -> f32 [M,N]                            (output projection)
// Tile layout (per 64-key tile, rows 128B): granule g (16B) stored at
// position g ^ (row & 7)  -> global_load_lds lands it swizzled in LDS.
// ---------------------------------------------------------------------------
template <int MODE>
__global__ __launch_bounds__(256)
void gemm_bf(const void* __restrict__ Av, const u16* __restrict__ Wb,
             void* __restrict__ Cv, float oscale)
{
    __shared__ u16 As[128 * 32];
    __shared__ u16 Bs[128 * 32];

    const int m0 = blockIdx.y * 128, n0 = blockIdx.x * 128;
    const int t = threadIdx.x, lane = t & 63, w = t >> 6;
    const int wr = (w >> 1) * 64, wc = (w & 1) * 64;
    const int lr = lane & 15, lg = lane >> 4;

    const int srow = t >> 2;                         // 0..63
    const int cc   = (t & 3) ^ ((t >> 3) & 3);       // swizzled 16B chunk
    const int fcol = (lg ^ ((lr >> 1) & 3)) * 8;     // swizzled read col

    const u16* Brow = Wb + (long)(n0 + srow) * 1024 + cc * 8;
    f32x4 acc[4][4] = {};

    for (int k0 = 0; k0 < 1024; k0 += 32) {
        gload16(Brow + k0,             Bs + w * 512);
        gload16(Brow + 64 * 1024 + k0, Bs + 2048 + w * 512);
        if (MODE == 1) {
            const u16* Arow = (const u16*)Av + (long)(m0 + srow) * 1024 + cc * 8;
            gload16(Arow + k0,             As + w * 512);
            gload16(Arow + 64 * 1024 + k0, As + 2048 + w * 512);
        } else {
            const float* Af = (const float*)Av + (long)(m0 + srow) * 1024 + (t & 3) * 8;
            #pragma unroll
            for (int c = 0; c < 2; ++c) {
                const float* p = Af + (long)c * 64 * 1024 + k0;
                f32x4 a = *(const f32x4*)(p), b = *(const f32x4*)(p + 4);
                s16x8 o;
                #pragma unroll
                for (int j = 0; j < 4; ++j) { o[j] = fb(a[j]); o[4 + j] = fb(b[j]); }
                *(s16x8*)(&As[(c * 64 + srow) * 32 + cc * 8]) = o;
            }
        }
        __syncthreads();

        s16x8 af[4], bfr[4];
        #pragma unroll
        for (int i = 0; i < 4; ++i)
            af[i] = *(const s16x8*)(&As[(wr + i * 16 + lr) * 32 + fcol]);
        #pragma unroll
        for (int i = 0; i < 4; ++i)
            bfr[i] = *(const s16x8*)(&Bs[(wc + i * 16 + lr) * 32 + fcol]);
        #pragma unroll
        for (int mi = 0; mi < 4; ++mi)
            #pragma unroll
            for (int ni = 0; ni < 4; ++ni)
                acc[mi][ni] = __builtin_amdgcn_mfma_f32_16x16x32_bf16(
                    af[mi], bfr[ni], acc[mi][ni], 0, 0, 0);
        __syncthreads();
    }

    if (MODE == 0) {
        u16* Cb = (u16*)Cv;                          // [B,H,S,Dh]
        #pragma unroll
        for (int mi = 0; mi < 4; ++mi)
            #pragma unroll
            for (int ni = 0; ni < 4; ++ni) {
                int col = n0 + wc + ni * 16 + lr;
                int h = col >> 6, dh = col & 63;
                #pragma unroll
                for (int r = 0; r < 4; ++r) {
                    int row = m0 + wr + mi * 16 + lg * 4 + r;
                    int b = row >> 11, s = row & 2047;
                    Cb[(((long)b * H_ + h) * S_ + s) * Dh_ + dh] =
                        (u16)fb(acc[mi][ni][r] * oscale);
                }
            }
    } else if (MODE == 3) {
        u16* Cb = (u16*)Cv;                          // K swizzled tiles
        #pragma unroll
        for (int mi = 0; mi < 4; ++mi)
            #pragma unroll
            for (int ni = 0; ni < 4; ++ni) {
                int col = n0 + wc + ni * 16 + lr;
                int h = col >> 6, dh = col & 63;
                #pragma unroll
                for (int r = 0; r < 4; ++r) {
                    int row = m0 + wr + mi * 16 + lg * 4 + r;
                    int b = row >> 11, s = row & 2047;
                    long idx = ((long)(b * H_ + h)) * 131072 + ((long)(s >> 6) << 12)
                             + ((s & 63) << 6) + (((dh >> 3) ^ (s & 7)) << 3) + (dh & 7);
                    Cb[idx] = (u16)fb(acc[mi][ni][r]);
                }
            }
    } else if (MODE == 2) {
        u16* Cb = (u16*)Cv;                          // V^T swizzled tiles
        #pragma unroll
        for (int mi = 0; mi < 4; ++mi)
            #pragma unroll
            for (int ni = 0; ni < 4; ++ni) {
                int col = n0 + wc + ni * 16 + lr;
                int h = col >> 6, dh = col & 63;
                int row = m0 + wr + mi * 16 + lg * 4;     // 4 consecutive tokens
                int b = row >> 11, k = row & 2047;
                long idx = ((long)(b * H_ + h)) * 131072 + ((long)(k >> 6) << 12)
                         + (dh << 6) + ((((k >> 3) & 7) ^ (dh & 7)) << 3) + (k & 7);
                union { short h4[4]; unsigned long long u; } pk;
                #pragma unroll
                for (int r = 0; r < 4; ++r) pk.h4[r] = fb(acc[mi][ni][r]);
                *(unsigned long long*)(&Cb[idx]) = pk.u;
            }
    } else {
        float* C = (float*)Cv;                       // [M,1024] f32
        #pragma unroll
        for (int mi = 0; mi < 4; ++mi)
            #pragma unroll
            for (int ni = 0; ni < 4; ++ni) {
                int col = n0 + wc + ni * 16 + lr;
                #pragma unroll
                for (int r = 0; r < 4; ++r) {
                    int row = m0 + wr + mi * 16 + lg * 4 + r;
                    C[(long)row * 1024 + col] = acc[mi][ni][r];
                }
            }
    }
}

// ---------------------------------------------------------------------------
// Causal flash attention v5: LDS-staged block-flash.
// 1 block = 8 waves (512 thr) = 256 q-rows of one (b,h); wave w owns rows
// [qb*256+w*32, +32). Block handles q-block pair (p, 7-p) -> uniform 36
// k-blocks; grid = 256 = 1 block/CU, zero imbalance.
// Per 64-key block: K (64x128B) + V^T (64x128B) tiles staged cooperatively
// via global_load_lds from PRE-SWIZZLED workspace (granule ^= row&7),
// double-buffered; stage kb+1 overlaps compute kb (2-phase pipeline).
// ---------------------------------------------------------------------------
__global__ __launch_bounds__(512)
void attn(const u16* __restrict__ Qp, const u16* __restrict__ Kws,
          const u16* __restrict__ Vws, u16* __restrict__ Op)
{
    __shared__ u16 Klds[2][4096];
    __shared__ u16 Vlds[2][4096];

    const int t = threadIdx.x, lane = t & 63, w = t >> 6;
    const int lr = lane & 15, lg = lane >> 4;
    const int bh = blockIdx.x & 63, pair = blockIdx.x >> 6;   // pair 0..3
    const int b = bh >> 4, h = bh & 15;

    const u16* Kb = Kws + (long)bh * 131072;
    const u16* Vb = Vws + (long)bh * 131072;

    #pragma unroll 1
    for (int sp = 0; sp < 2; ++sp) {
        const int qb = sp ? (7 - pair) : pair;
        const int q0w = qb * 256 + w * 32;
        const u16* Qbp = Qp + ((long)bh * S_ + q0w) * Dh_;

        s16x8 qf[2][2];
        #pragma unroll
        for (int i = 0; i < 2; ++i)
            #pragma unroll
            for (int hh = 0; hh < 2; ++hh)
                qf[i][hh] = *(const s16x8*)(Qbp + (i * 16 + lr) * Dh_ + hh * 32 + lg * 8);

        f32x4 acc[2][4] = {};
        float mrun[2] = { -1e30f, -1e30f }, lrun[2] = { 0.0f, 0.0f };
        const int nkb = (qb + 1) * 4;

        // prologue: stage kb=0 (each wave stages 1KB of K and 1KB of V)
        gload16(Kb + w * 512 + lane * 8, &Klds[0][w * 512]);
        gload16(Vb + w * 512 + lane * 8, &Vlds[0][w * 512]);
        __syncthreads();

        #pragma unroll 1
        for (int kb = 0; kb < nkb; ++kb) {
            const int cur = kb & 1;
            const int k0 = kb * 64;
            if (kb + 1 < nkb) {
                const long off = (long)(kb + 1) * 4096 + w * 512 + lane * 8;
                gload16(Kb + off, &Klds[cur ^ 1][w * 512]);
                gload16(Vb + off, &Vlds[cur ^ 1][w * 512]);
            }
            if (k0 <= q0w + 31) {
                // ---- QK^T from swizzled K tile ----
                f32x4 st[2][4] = {};
                const int r7 = lr & 7;
                __builtin_amdgcn_s_setprio(1);
                #pragma unroll
                for (int kt = 0; kt < 4; ++kt) {
                    const int rb = (kt * 16 + lr) * 64;
                    s16x8 kf0 = *(const s16x8*)(&Klds[cur][rb + ((lg ^ r7) << 3)]);
                    s16x8 kf1 = *(const s16x8*)(&Klds[cur][rb + (((4 + lg) ^ r7) << 3)]);
                    #pragma unroll
                    for (int i = 0; i < 2; ++i) {
                        st[i][kt] = __builtin_amdgcn_mfma_f32_16x16x32_bf16(
                            kf0, qf[i][0], st[i][kt], 0, 0, 0);
                        st[i][kt] = __builtin_amdgcn_mfma_f32_16x16x32_bf16(
                            kf1, qf[i][1], st[i][kt], 0, 0, 0);
                    }
                }
                __builtin_amdgcn_s_setprio(0);

                // ---- softmax (exp2 domain, deferred max) ----
                const bool dmask = (k0 + 63) > q0w;
                s16x4 pb[2][4];
                #pragma unroll
                for (int i = 0; i < 2; ++i) {
                    const int qg = q0w + i * 16 + lr;
                    float sv[16];
                    #pragma unroll
                    for (int kt = 0; kt < 4; ++kt)
                        #pragma unroll
                        for (int r = 0; r < 4; ++r) {
                            float sc = st[i][kt][r];
                            if (dmask && (k0 + kt * 16 + lg * 4 + r) > qg) sc = -1e30f;
                            sv[kt * 4 + r] = sc;
                        }
                    float tm = sv[0];
                    #pragma unroll
                    for (int e = 1; e < 16; ++e) tm = fmaxf(tm, sv[e]);
                    tm = fmaxf(tm, __shfl_xor(tm, 16));
                    tm = fmaxf(tm, __shfl_xor(tm, 32));
                    float mnew = mrun[i];
                    if (!__all(tm <= mrun[i] + 8.0f)) {      // T13 defer-max
                        mnew = fmaxf(mrun[i], tm);
                        float f = __builtin_amdgcn_exp2f(mrun[i] - mnew);
                        lrun[i] *= f;
                        #pragma unroll
                        for (int tt = 0; tt < 4; ++tt) acc[i][tt] *= f;
                        mrun[i] = mnew;
                    }
                    float psum = 0.0f;
                    #pragma unroll
                    for (int kt = 0; kt < 4; ++kt) {
                        short ph[4];
                        #pragma unroll
                        for (int r = 0; r < 4; ++r) {
                            float p = __builtin_amdgcn_exp2f(sv[kt * 4 + r] - mnew);
                            psum += p;
                            ph[r] = fb(p);
                        }
                        pb[i][kt] = (s16x4){ ph[0], ph[1], ph[2], ph[3] };
                    }
                    psum += __shfl_xor(psum, 16);
                    psum += __shfl_xor(psum, 32);
                    lrun[i] += psum;
                }

                // ---- PV from swizzled V^T tile ----
                __builtin_amdgcn_s_setprio(1);
                #pragma unroll
                for (int kt = 0; kt < 4; ++kt)
                    #pragma unroll
                    for (int tt = 0; tt < 4; ++tt) {
                        const int rb = (tt * 16 + lr) * 64;
                        const int gsw = (kt * 2 + (lg >> 1)) ^ r7;
                        s16x4 vf = *(const s16x4*)
                            (&Vlds[cur][rb + (gsw << 3) + ((lg & 1) << 2)]);
                        acc[0][tt] = __builtin_amdgcn_mfma_f32_16x16x16bf16_1k(
                            vf, pb[0][kt], acc[0][tt], 0, 0, 0);
                        acc[1][tt] = __builtin_amdgcn_mfma_f32_16x16x16bf16_1k(
                            vf, pb[1][kt], acc[1][tt], 0, 0, 0);
                    }
                __builtin_amdgcn_s_setprio(0);
            }
            __syncthreads();
        }

        // ---- epilogue: O[b,q,h,dh] bf16 ----
        #pragma unroll
        for (int i = 0; i < 2; ++i) {
            const float inv = 1.0f / lrun[i];
            u16* ob = Op + (((long)b * S_ + q0w + i * 16 + lr) * H_ + h) * Dh_;
            #pragma unroll
            for (int tt = 0; tt < 4; ++tt) {
                union { short h4[4]; unsigned long long u; } pk;
                #pragma unroll
                for (int r = 0; r < 4; ++r) pk.h4[r] = fb(acc[i][tt][r] * inv);
                *(unsigned long long*)(ob + tt * 16 + lg * 4) = pk.u;
            }
        }
    }
}

// ---------------------------------------------------------------------------
extern "C" void kernel_launch(void* const* d_in, const int* in_sizes, int n_in,
                              void* d_out, int out_size, void* d_ws, size_t ws_size,
                              hipStream_t stream)
{
    const float* q  = (const float*)d_in[0];
    const float* k  = (const float*)d_in[1];
    const float* v  = (const float*)d_in[2];
    // d_in[3] = causal mask — hardcoded
    const float* Wq = (const float*)d_in[4];
    const float* Wk = (const float*)d_in[5];
    const float* Wv = (const float*)d_in[6];
    const float* Wo = (const float*)d_in[7];

    u16* ws = (u16*)d_ws;
    const long NE = (long)B_ * S_ * D_;           // 8388608 elems
    const long WE = (long)D_ * D_;                // 1048576 elems
    u16* Qp  = ws;                                 // [B,H,S,Dh]
    u16* Kws_ = ws + NE;                           // K swizzled tiles
    u16* Vws_ = ws + 2 * NE;                       // V^T swizzled tiles
    u16* Op  = ws + 3 * NE;                        // [B,S,H,Dh]
    u16* WqB = Op;            // dead before attn writes Op
    u16* WkB = Op + WE;
    u16* WvB = Op + 2 * WE;
    u16* WoB = Qp;            // Qp dead after attn

    dim3 gw(512, 3), gw1(512, 1), gg(8, 64), blk(256);
    hipLaunchKernelGGL(cvtW, gw, blk, 0, stream, Wq, Wk, Wv, WqB, WkB, WvB);
    hipLaunchKernelGGL((gemm_bf<0>), gg, blk, 0, stream, q, WqB, Qp, QSCALE);
    hipLaunchKernelGGL((gemm_bf<3>), gg, blk, 0, stream, k, WkB, Kws_, 1.0f);
    hipLaunchKernelGGL((gemm_bf<2>), gg, blk, 0, stream, v, WvB, Vws_, 1.0f);
    hipLaunchKernelGGL(attn, dim3(256), dim3(512), 0, stream, Qp, Kws_, Vws_, Op);
    hipLaunchKernelGGL(cvtW, gw1, blk, 0, stream, Wo, Wo, Wo, WoB, WoB, WoB);
    hipLaunchKernelGGL((gemm_bf<1>), gg, blk, 0, stream, Op, WoB, (float*)d_out, 1.0f);
}